// Round 4
// baseline (3031.163 us; speedup 1.0000x reference)
//
#include <hip/hip_runtime.h>
#include <cstdint>
#include <cstddef>

// ============================================================================
// new_clsnet on MI355X — round 4: fp32 inputs/outputs (reference dtypes!),
// bf16 MFMA internally, fp32 staged to LDS + in-register bf16 convert.
// Theory: r1-r3 failures were dtype misread (inputs are float32; reading them
// as bf16 produced NaN-patterned garbage -> NaN out0 (r1/r3) and all-NaN
// distances -> sentinel index -> wild gather crash (r2)).
//
// Distance GEMM uses in-register hi/lo bf16 split of both operands
// (3 MFMA passes: hh + h*lo + lo*h) for fp32-grade argmin accuracy.
// Batch chunked x4 => ws peak ~33 MiB.
//
// ws: [0,0.5M) small | [1M,9M) G bf16 | [9M,33M) chunk region:
//     KwT@9M/QwT@17M (transient) -> flat_c@9M (16M) + h_c@25M (8M)
// ============================================================================

typedef __bf16 bf16;
typedef __bf16 bf16x8 __attribute__((ext_vector_type(8)));
typedef float  f32x4  __attribute__((ext_vector_type(4)));

#define TO_AS1(p) ((__attribute__((address_space(1))) void*)(uintptr_t)(p))
#define TO_AS3(p) ((__attribute__((address_space(3))) void*)(uintptr_t)(p))

enum { EPI_BF16 = 0, EPI_DIST = 1, EPI_SCORES = 2, EPI_RELU = 3, EPI_BIAS = 4 };

// stage one 128xBK(=64-elem) tile, 16B chunks; LDS dest = uniform base,
// HW scatters lane*16 (global_load_lds contract).
template <bool F32C>
__device__ __forceinline__ void stage_op(const char* __restrict__ src,
                                         char* lds, int rbase, int ld, int k0,
                                         int clamp, int tid) {
  constexpr int IT = F32C ? 8 : 4;    // 16B chunks per thread
  constexpr int CPR = F32C ? 16 : 8;  // chunks per 64-elem row
  constexpr int EB = F32C ? 4 : 2;    // bytes per element
  const int wb = tid & ~63;           // wave*64
  const int lane = tid & 63;
#pragma unroll
  for (int it = 0; it < IT; ++it) {
    const int chunk = it * 256 + wb + lane;
    int row = rbase + chunk / CPR;
    if (row > clamp) row = clamp;
    const int cel = (chunk % CPR) * (16 / EB);
    const char* gp = src + ((size_t)row * ld + k0 + cel) * EB;
    __builtin_amdgcn_global_load_lds(TO_AS1(gp),
                                     TO_AS3(lds + (it * 256 + wb) * 16), 16, 0,
                                     0);
  }
}

// load 8-elem fragment from LDS; fp32 path converts to bf16 hi (+lo)
template <bool F32C, bool WANTLO>
__device__ __forceinline__ void frag_ld(const char* lds, int r, int koff,
                                        bf16x8& hi, bf16x8& lo) {
  if constexpr (F32C) {
    const float* p = (const float*)lds + r * 64 + koff;
    f32x4 v0 = *(const f32x4*)p;
    f32x4 v1 = *(const f32x4*)(p + 4);
#pragma unroll
    for (int t = 0; t < 4; ++t) { hi[t] = (bf16)v0[t]; hi[4 + t] = (bf16)v1[t]; }
    if constexpr (WANTLO) {
#pragma unroll
      for (int t = 0; t < 4; ++t) {
        lo[t] = (bf16)(v0[t] - (float)hi[t]);
        lo[4 + t] = (bf16)(v1[t] - (float)hi[4 + t]);
      }
    }
  } else {
    hi = *(const bf16x8*)((const bf16*)lds + r * 64 + koff);
    (void)lo;
  }
}

// ---------------------------------------------------------------------------
// C[m,n] = sum_k A[m,k]*B[n,k]; 128x128 tile, BK=64, 256 thr, mfma 16x16x32.
// AF32/BF32: operand dtype fp32 (LDS-staged raw, converted in-register).
// TRIPLE: hi/lo product (dist only).
// ---------------------------------------------------------------------------
template <int EPI, bool AF32, bool BF32, bool TRIPLE>
__global__ __launch_bounds__(256, 2) void gemm_nt(
    const void* __restrict__ A, const void* __restrict__ B,
    void* __restrict__ Cout, const float* __restrict__ bias,
    const float* __restrict__ qp, const float* __restrict__ fp,
    float* __restrict__ sA, float* __restrict__ sB,
    const float* __restrict__ nx, const float* __restrict__ nw,
    const float* __restrict__ sw, float* __restrict__ Dmin,
    int* __restrict__ Darg, int K, int lda, int ldb, int ldc, int nclamp) {
  __shared__ __align__(16) char AsRaw[AF32 ? 32768 : 16384];
  __shared__ __align__(16) char BsRaw[BF32 ? 32768 : 16384];

  const int tid = threadIdx.x;
  const int wave = tid >> 6, lane = tid & 63;
  const int bm = blockIdx.x * 128, bn = blockIdx.y * 128;

  f32x4 acc[4][4] = {};

  const int fm = lane & 15;
  const int fk = (lane >> 4) * 8;
  const int wm = (wave >> 1) * 64;
  const int wn = (wave & 1) * 64;

  for (int k0 = 0; k0 < K; k0 += 64) {
    stage_op<AF32>((const char*)A, AsRaw, bm, lda, k0, 1 << 30, tid);
    stage_op<BF32>((const char*)B, BsRaw, bn, ldb, k0, nclamp, tid);
    __builtin_amdgcn_s_waitcnt(0);
    __syncthreads();
#pragma unroll
    for (int ks = 0; ks < 2; ++ks) {
      bf16x8 ah[4], al[4], bh[4], bl[4];
#pragma unroll
      for (int i = 0; i < 4; ++i)
        frag_ld<AF32, TRIPLE>(AsRaw, wm + 16 * i + fm, ks * 32 + fk, ah[i], al[i]);
#pragma unroll
      for (int j = 0; j < 4; ++j)
        frag_ld<BF32, TRIPLE>(BsRaw, wn + 16 * j + fm, ks * 32 + fk, bh[j], bl[j]);
#pragma unroll
      for (int i = 0; i < 4; ++i)
#pragma unroll
        for (int j = 0; j < 4; ++j) {
          acc[i][j] = __builtin_amdgcn_mfma_f32_16x16x32_bf16(ah[i], bh[j],
                                                              acc[i][j], 0, 0, 0);
          if constexpr (TRIPLE) {
            acc[i][j] = __builtin_amdgcn_mfma_f32_16x16x32_bf16(
                ah[i], bl[j], acc[i][j], 0, 0, 0);
            acc[i][j] = __builtin_amdgcn_mfma_f32_16x16x32_bf16(
                al[i], bh[j], acc[i][j], 0, 0, 0);
          }
        }
    }
    __syncthreads();
  }

  // epilogue; C/D layout: col=lane&15, row=(lane>>4)*4+r (m89-verified)
  const int r0 = (lane >> 4) * 4;

  if constexpr (EPI == EPI_DIST) {
    __shared__ float vred[256];
    __shared__ int ared[256];
    const float INF = 3.4e38f;
#pragma unroll
    for (int i = 0; i < 4; ++i) {
#pragma unroll
      for (int r = 0; r < 4; ++r) {
        const int rl = wm + 16 * i + r0 + r;
        const float rx = nx[bm + rl];
        float best = INF;
        int barg = 0;
#pragma unroll
        for (int j = 0; j < 4; ++j) {
          const int col = bn + wn + 16 * j + fm;
          if (col <= nclamp) {
            float s = sw[col] - 2.0f * acc[i][j][r] / (rx * nw[col]);
            if (s < best) { best = s; barg = col; }
          }
        }
#pragma unroll
        for (int o = 8; o >= 1; o >>= 1) {
          float ob = __shfl_xor(best, o, 64);
          int oa = __shfl_xor(barg, o, 64);
          if (ob < best || (ob == best && oa < barg)) { best = ob; barg = oa; }
        }
        if (fm == 0) {
          vred[rl * 2 + (wave & 1)] = best;
          ared[rl * 2 + (wave & 1)] = barg;
        }
      }
    }
    __syncthreads();
    if (tid < 128) {
      float v0 = vred[tid * 2], v1 = vred[tid * 2 + 1];
      int a0 = ared[tid * 2], a1 = ared[tid * 2 + 1];
      float bv = v0; int ba = a0;
      if (v1 < bv || (v1 == bv && a1 < ba)) { bv = v1; ba = a1; }
      Dmin[(size_t)(bm + tid) * 8 + blockIdx.y] = bv;
      Darg[(size_t)(bm + tid) * 8 + blockIdx.y] = ba;
    }
    return;
  }

  if constexpr (EPI == EPI_SCORES) {
#pragma unroll
    for (int i = 0; i < 4; ++i) {
#pragma unroll
      for (int r = 0; r < 4; ++r) {
        const int row = bm + wm + 16 * i + r0 + r;
        float pa = 0.f, pb = 0.f;
#pragma unroll
        for (int j = 0; j < 4; ++j) {
          const int col = bn + wn + 16 * j + fm;
          const float c = acc[i][j][r];
          pa += qp[(size_t)row * 2048 + col] * c;
          pb += fp[(size_t)row * 2048 + col] * c;
        }
#pragma unroll
        for (int o = 8; o >= 1; o >>= 1) {
          pa += __shfl_xor(pa, o, 64);
          pb += __shfl_xor(pb, o, 64);
        }
        if (fm == 0) { atomicAdd(&sA[row], pa); atomicAdd(&sB[row], pb); }
      }
    }
    return;
  }

#pragma unroll
  for (int i = 0; i < 4; ++i) {
#pragma unroll
    for (int j = 0; j < 4; ++j) {
      const int col = bn + wn + 16 * j + fm;
#pragma unroll
      for (int r = 0; r < 4; ++r) {
        const int row = bm + wm + 16 * i + r0 + r;
        float c = acc[i][j][r];
        if constexpr (EPI == EPI_BF16) {
          ((bf16*)Cout)[(size_t)row * ldc + col] = (bf16)c;
        } else if constexpr (EPI == EPI_RELU) {
          float v = c + bias[col];
          ((bf16*)Cout)[(size_t)row * ldc + col] = (bf16)(v > 0.f ? v : 0.f);
        } else {  // EPI_BIAS: fp32 out, ragged-guarded
          int bc = col <= nclamp ? col : nclamp;
          float v = c + bias[bc];
          if (col <= nclamp) ((float*)Cout)[(size_t)row * ldc + col] = v;
        }
      }
    }
  }
}

// ---------------------------------------------------------------------------
__global__ void zero_k(float* __restrict__ p) {
  p[blockIdx.x * 256 + threadIdx.x] = 0.f;
}

// fp32 2048x2048 transpose -> bf16 K-contiguous operands for G
__global__ void transpose2_k(const float* __restrict__ Kw,
                             const float* __restrict__ Qw,
                             bf16* __restrict__ KwT, bf16* __restrict__ QwT) {
  __shared__ float tile[64][65];
  const float* src = blockIdx.z ? Qw : Kw;
  bf16* dst = blockIdx.z ? QwT : KwT;
  const int bx = blockIdx.x * 64, by = blockIdx.y * 64;
  const int tx = threadIdx.x & 63, ty = threadIdx.x >> 6;
  for (int r = ty; r < 64; r += 4)
    tile[r][tx] = src[(size_t)(by + r) * 2048 + bx + tx];
  __syncthreads();
  for (int r = ty; r < 64; r += 4)
    dst[(size_t)(bx + r) * 2048 + by + tx] = (bf16)tile[tx][r];
}

__device__ __forceinline__ float block_sum(float v, float* sbuf) {
#pragma unroll
  for (int o = 32; o > 0; o >>= 1) v += __shfl_down(v, o, 64);
  const int wave = threadIdx.x >> 6, lane = threadIdx.x & 63;
  if (lane == 0) sbuf[wave] = v;
  __syncthreads();
  float r = sbuf[0] + sbuf[1] + sbuf[2] + sbuf[3];
  __syncthreads();
  return r;
}

__global__ void feat_norm_k(const float* __restrict__ x, float* __restrict__ nx) {
  __shared__ float sbuf[4];
  const float* row = x + (size_t)blockIdx.x * 2048;
  f32x4 a = *(const f32x4*)(row + threadIdx.x * 8);
  f32x4 b = *(const f32x4*)(row + threadIdx.x * 8 + 4);
  float s = 0.f;
#pragma unroll
  for (int t = 0; t < 4; ++t) s += a[t] * a[t] + b[t] * b[t];
  float tot = block_sum(s, sbuf);
  if (threadIdx.x == 0) nx[blockIdx.x] = fmaxf(sqrtf(tot), 1e-12f);
}

__global__ void emb_norm_k(const float* __restrict__ w, float* __restrict__ nw,
                           float* __restrict__ sw) {
  __shared__ float sbuf[4];
  const float* row = w + (size_t)blockIdx.x * 2048;
  f32x4 a = *(const f32x4*)(row + threadIdx.x * 8);
  f32x4 b = *(const f32x4*)(row + threadIdx.x * 8 + 4);
  float s = 0.f;
#pragma unroll
  for (int t = 0; t < 4; ++t) s += a[t] * a[t] + b[t] * b[t];
  float n = fmaxf(sqrtf(block_sum(s, sbuf)), 1e-12f);
  float s2 = 0.f;
#pragma unroll
  for (int t = 0; t < 4; ++t) {
    float va = a[t] / n, vb = b[t] / n;
    s2 += va * va + vb * vb;
  }
  float tot2 = block_sum(s2, sbuf);
  if (threadIdx.x == 0) { nw[blockIdx.x] = n; sw[blockIdx.x] = tot2; }
}

__global__ void argmin_final_k(const float* __restrict__ Dmin,
                               const int* __restrict__ Darg,
                               const float* __restrict__ emb,
                               float* __restrict__ qout,
                               float* __restrict__ idxout) {
  const int b = blockIdx.x, tid = threadIdx.x;
  __shared__ int sidx;
  if (tid == 0) {
    float best = 3.4e38f;
    int idx = 0;
    bool found = false;
    for (int t = 0; t < 8; ++t) {
      float v = Dmin[(size_t)b * 8 + t];
      int a = Darg[(size_t)b * 8 + t];
      if (!(v == v) || a < 0 || a >= 1000) continue;
      if (!found || v < best || (v == best && a < idx)) {
        best = v; idx = a; found = true;
      }
    }
    if (idx < 0) idx = 0;
    if (idx > 999) idx = 999;
    sidx = idx;
    idxout[b] = (float)idx;
  }
  __syncthreads();
  const f32x4* src = (const f32x4*)(emb + (size_t)sidx * 2048);
  f32x4* dst = (f32x4*)(qout + (size_t)b * 2048);
  dst[tid] = src[tid];
  dst[tid + 256] = src[tid + 256];
}

__global__ void scores_final_k(const float* __restrict__ s00p,
                               const float* __restrict__ s10p,
                               const float* __restrict__ s01p,
                               const float* __restrict__ s11p,
                               float* __restrict__ Amat) {
  const int b = blockIdx.x * 256 + threadIdx.x;
  float t00 = s00p[b], t10 = s10p[b], t01 = s01p[b], t11 = s11p[b];
  float m0 = fmaxf(t00, t10), m1 = fmaxf(t01, t11);
  float e00 = expf(t00 - m0), e10 = expf(t10 - m0);
  float e01 = expf(t01 - m1), e11 = expf(t11 - m1);
  float d0 = e00 + e10, d1 = e01 + e11;
  float* Ab = Amat + (size_t)b * 4;
  Ab[0] = e00 / d0; Ab[1] = e10 / d0; Ab[2] = e01 / d1; Ab[3] = e11 / d1;
}

__global__ void combine_k(const float* __restrict__ Amat, bf16* __restrict__ flat) {
  const int b = blockIdx.x;
  const int i = threadIdx.x * 8;
  const float a00 = Amat[(size_t)b * 4 + 0], a10 = Amat[(size_t)b * 4 + 1];
  const float a01 = Amat[(size_t)b * 4 + 2], a11 = Amat[(size_t)b * 4 + 3];
  bf16x8 v0 = *(const bf16x8*)(flat + (size_t)b * 4096 + i);
  bf16x8 v1 = *(const bf16x8*)(flat + (size_t)b * 4096 + 2048 + i);
  bf16x8 L, R;
#pragma unroll
  for (int t = 0; t < 8; ++t) {
    float x0 = (float)v0[t], x1 = (float)v1[t];
    L[t] = (bf16)(a00 * x0 + a10 * x1);
    R[t] = (bf16)(a01 * x0 + a11 * x1);
  }
  *(bf16x8*)(flat + (size_t)b * 4096 + i) = L;
  *(bf16x8*)(flat + (size_t)b * 4096 + 2048 + i) = R;
}

// ---------------------------------------------------------------------------
extern "C" void kernel_launch(void* const* d_in, const int* in_sizes, int n_in,
                              void* d_out, int out_size, void* d_ws,
                              size_t ws_size, hipStream_t stream) {
  const float* feat = (const float*)d_in[0];
  const float* emb = (const float*)d_in[1];
  const float* Kw = (const float*)d_in[2];
  const float* Qw = (const float*)d_in[3];
  const float* Vw = (const float*)d_in[4];
  const float* fuse_w = (const float*)d_in[5];
  const float* fuse_b = (const float*)d_in[6];
  const float* fc_w = (const float*)d_in[7];
  const float* fc_b = (const float*)d_in[8];

  float* out_q = (float*)d_out;                     // 8192*2048
  float* out_pred = out_q + (size_t)8192 * 2048;    // 8192*1000
  float* out_idx = out_pred + (size_t)8192 * 1000;  // 8192

  char* ws = (char*)d_ws;
  const size_t MiB = 1024 * 1024;
  float* nx = (float*)(ws + 0);            // 32 KB
  float* nw = (float*)(ws + 32768);        // 4 KB
  float* swp = (float*)(ws + 36864);       // 4 KB
  float* sb4 = (float*)(ws + 40960);       // 128 KB: s00|s10|s01|s11 (8192 ea)
  float* Amat = (float*)(ws + 172032);     // 128 KB
  float* Dmin = (float*)(ws + 303104);     // 64 KB (2048x8)
  int* Darg = (int*)(ws + 368640);         // 64 KB
  bf16* G = (bf16*)(ws + 1 * MiB);         // 8 MB  [1,9)
  bf16* KwT = (bf16*)(ws + 9 * MiB);       // 8 MB  [9,17)  transient
  bf16* QwT = (bf16*)(ws + 17 * MiB);      // 8 MB  [17,25) transient
  bf16* flat_c = (bf16*)(ws + 9 * MiB);    // 16 MB [9,25)  per chunk
  bf16* h_c = (bf16*)(ws + 25 * MiB);      // 8 MB  [25,33) per chunk

  zero_k<<<128, 256, 0, stream>>>(sb4);
  feat_norm_k<<<8192, 256, 0, stream>>>(feat, nx);
  emb_norm_k<<<1000, 256, 0, stream>>>(emb, nw, swp);
  transpose2_k<<<dim3(32, 32, 2), 256, 0, stream>>>(Kw, Qw, KwT, QwT);
  // G = Kw^T Qw (bf16 operands, bf16 out)
  gemm_nt<EPI_BF16, false, false, false><<<dim3(16, 16), 256, 0, stream>>>(
      KwT, QwT, G, nullptr, nullptr, nullptr, nullptr, nullptr, nullptr,
      nullptr, nullptr, nullptr, nullptr, 2048, 2048, 2048, 2048, 2047);

  for (int c = 0; c < 4; ++c) {
    const size_t off = (size_t)c * 2048;
    const float* feat_c = feat + off * 2048;
    float* outq_c = out_q + off * 2048;
    // distance GEMM (fp32 operands, hi/lo triple) + fused scaled argmin
    gemm_nt<EPI_DIST, true, true, true><<<dim3(16, 8), 256, 0, stream>>>(
        feat_c, emb, nullptr, nullptr, nullptr, nullptr, nullptr, nullptr,
        nx + off, nw, swp, Dmin, Darg, 2048, 2048, 2048, 0, 999);
    argmin_final_k<<<2048, 256, 0, stream>>>(Dmin, Darg, emb, outq_c,
                                             out_idx + off);
    // S-gemms: (G q) and (G f), fused score dots
    gemm_nt<EPI_SCORES, true, false, false><<<dim3(16, 16), 256, 0, stream>>>(
        outq_c, G, nullptr, nullptr, outq_c, feat_c, sb4 + off,
        sb4 + 8192 + off, nullptr, nullptr, nullptr, nullptr, nullptr, 2048,
        2048, 2048, 0, 2047);
    gemm_nt<EPI_SCORES, true, false, false><<<dim3(16, 16), 256, 0, stream>>>(
        feat_c, G, nullptr, nullptr, outq_c, feat_c, sb4 + 16384 + off,
        sb4 + 24576 + off, nullptr, nullptr, nullptr, nullptr, nullptr, 2048,
        2048, 2048, 0, 2047);
    scores_final_k<<<8, 256, 0, stream>>>(sb4 + off, sb4 + 8192 + off,
                                          sb4 + 16384 + off, sb4 + 24576 + off,
                                          Amat + off * 4);
    // V-gemms -> flat halves (bf16, ldc 4096)
    gemm_nt<EPI_BF16, true, true, false><<<dim3(16, 16), 256, 0, stream>>>(
        outq_c, Vw, flat_c, nullptr, nullptr, nullptr, nullptr, nullptr,
        nullptr, nullptr, nullptr, nullptr, nullptr, 2048, 2048, 2048, 4096,
        2047);
    gemm_nt<EPI_BF16, true, true, false><<<dim3(16, 16), 256, 0, stream>>>(
        feat_c, Vw, flat_c + 2048, nullptr, nullptr, nullptr, nullptr, nullptr,
        nullptr, nullptr, nullptr, nullptr, nullptr, 2048, 2048, 2048, 4096,
        2047);
    combine_k<<<2048, 256, 0, stream>>>(Amat + off * 4, flat_c);
    // fuse: h = relu(flat @ fuse_w^T + b)   (A bf16, B fp32, K=4096)
    gemm_nt<EPI_RELU, false, true, false><<<dim3(16, 16), 256, 0, stream>>>(
        flat_c, fuse_w, h_c, fuse_b, nullptr, nullptr, nullptr, nullptr,
        nullptr, nullptr, nullptr, nullptr, nullptr, 4096, 4096, 4096, 2048,
        2047);
    // pred: fp32 out, ragged N=1000
    gemm_nt<EPI_BIAS, false, true, false><<<dim3(16, 8), 256, 0, stream>>>(
        h_c, fc_w, out_pred + off * 1000, fc_b, nullptr, nullptr, nullptr,
        nullptr, nullptr, nullptr, nullptr, nullptr, nullptr, 2048, 2048, 2048,
        1000, 999);
  }
}